// Round 1
// baseline (35234.442 us; speedup 1.0000x reference)
//
#include <hip/hip_runtime.h>
#include <hip/hip_bf16.h>

// EmbedAlign: emb gather -> 3-layer BiLSTM (seq scan) -> mu/sigma nets ->
// reparam z -> KL + negative-sampling scores + alignment marginal -> scalar.
// All fp32. D=512, L=1024, NNEG=8192, V=32000.

#define NW 32            // workgroups per scan direction

// ---------------------------------------------------------------------------
// Generic fp32 NT GEMM: C[M,N] = A[M,K] . B[N,K]^T (+bias) with epilogues.
// GATHER: B row n comes from B[idx[n]].  EPI: 0=store(+bias,+relu),
// 1=atomicAdd rowsum(exp(C)) into C-vector, 2=atomicAdd sum(exp/(exp+negf)).
// Tiles 64x64, BK=16, 256 threads, 4x4 per thread.
// ---------------------------------------------------------------------------
template<bool GATHER, bool RELU, int EPI>
__global__ __launch_bounds__(256) void gemm_nt(
    const float* __restrict__ A, const float* __restrict__ B,
    const float* __restrict__ bias, const int* __restrict__ idx,
    float* __restrict__ C, const float* __restrict__ negf,
    float* __restrict__ outsum, int M, int N, int K)
{
    __shared__ float As[16][68];
    __shared__ float Bs[16][68];
    __shared__ float wsum[4];

    const int tid = threadIdx.x;
    const int bm = blockIdx.x, bn = blockIdx.y;
    const int tx = tid & 15, ty = tid >> 4;
    const int lr = tid >> 2;          // 0..63: tile row being loaded
    const int lk = (tid & 3) * 4;     // 0,4,8,12: k sub-offset

    const long arow = (long)bm * 64 + lr;
    const int  brow = bn * 64 + lr;
    const long bsrc = GATHER ? (long)idx[brow] : (long)brow;
    const float* Ap = A + arow * K + lk;
    const float* Bp = B + bsrc * K + lk;

    float acc[4][4] = {};

    for (int k0 = 0; k0 < K; k0 += 16) {
        float4 av = *(const float4*)(Ap + k0);
        float4 bv = *(const float4*)(Bp + k0);
        __syncthreads();
        As[lk + 0][lr] = av.x; As[lk + 1][lr] = av.y;
        As[lk + 2][lr] = av.z; As[lk + 3][lr] = av.w;
        Bs[lk + 0][lr] = bv.x; Bs[lk + 1][lr] = bv.y;
        Bs[lk + 2][lr] = bv.z; Bs[lk + 3][lr] = bv.w;
        __syncthreads();
#pragma unroll
        for (int k = 0; k < 16; ++k) {
            float4 a = *(const float4*)&As[k][ty * 4];
            float4 b = *(const float4*)&Bs[k][tx * 4];
            float ar[4] = {a.x, a.y, a.z, a.w};
            float br[4] = {b.x, b.y, b.z, b.w};
#pragma unroll
            for (int i = 0; i < 4; ++i)
#pragma unroll
                for (int j = 0; j < 4; ++j)
                    acc[i][j] += ar[i] * br[j];
        }
    }

    const int row0 = bm * 64 + ty * 4, col0 = bn * 64 + tx * 4;

    if (EPI == 0) {
#pragma unroll
        for (int i = 0; i < 4; ++i) {
            float4 v;
            float vv[4];
#pragma unroll
            for (int j = 0; j < 4; ++j) {
                float x = acc[i][j];
                if (bias) x += bias[col0 + j];
                if (RELU) x = x > 0.f ? x : 0.f;
                vv[j] = x;
            }
            v.x = vv[0]; v.y = vv[1]; v.z = vv[2]; v.w = vv[3];
            *(float4*)&C[(long)(row0 + i) * N + col0] = v;
        }
    } else if (EPI == 1) {
        // per-row sum of exp over this tile's 64 cols -> atomicAdd C[row]
#pragma unroll
        for (int i = 0; i < 4; ++i) {
            float s = expf(acc[i][0]) + expf(acc[i][1]) +
                      expf(acc[i][2]) + expf(acc[i][3]);
            s += __shfl_xor(s, 1); s += __shfl_xor(s, 2);
            s += __shfl_xor(s, 4); s += __shfl_xor(s, 8);
            if (tx == 0) atomicAdd(&C[row0 + i], s);
        }
    } else {
        float t = 0.f;
#pragma unroll
        for (int i = 0; i < 4; ++i) {
            float nf = negf[row0 + i];
#pragma unroll
            for (int j = 0; j < 4; ++j) {
                float e = expf(acc[i][j]);
                t += e / (e + nf);
            }
        }
#pragma unroll
        for (int o = 1; o < 64; o <<= 1) t += __shfl_xor(t, o);
        if ((tid & 63) == 0) wsum[tid >> 6] = t;
        __syncthreads();
        if (tid == 0) atomicAdd(outsum, wsum[0] + wsum[1] + wsum[2] + wsum[3]);
    }
}

// ---------------------------------------------------------------------------
// BiLSTM scan over 1024 steps. Grid = 64 WGs x 256 threads:
// blocks 0..31 forward, 32..63 backward. Each WG owns 16 h-outputs (64 gate
// rows); Whh chunk (64 rows x 128 cols / thread-quad) lives in VGPRs for the
// whole scan. Per step: stage h_prev (512 f) into LDS, dot, 4-lane butterfly,
// gate nonlinearity by 16 state threads, write h, device-scope barrier.
// hbuf is double-buffered so writers of step s can't race readers of s-1.
// ---------------------------------------------------------------------------
__global__ __launch_bounds__(256, 1) void lstm_scan(
    const float* __restrict__ Xf, const float* __restrict__ Xb, // (1024,2048) pre-proj incl bias
    const float* __restrict__ Whh,                              // (2,2048,512)
    float* __restrict__ out,                                    // (1024,1024) [hf|hb]
    float* __restrict__ hbuf,                                   // (2 dirs,2 bufs,512), zeroed
    unsigned int* __restrict__ cnt)                             // zeroed; dir*32 stride
{
    const int tid  = threadIdx.x;
    const int dir  = blockIdx.x >> 5;
    const int w    = blockIdx.x & 31;
    const int r    = tid >> 2;        // 0..63 gate-row within WG
    const int ck   = tid & 3;         // col chunk 0..3 (128 cols each)
    const int gate = r >> 4;
    const int jl   = r & 15;
    const int j    = w * 16 + jl;     // h index 0..511
    const int grow = gate * 512 + j;  // row in (2048 x 512) Whh

    const float* Wrow = Whh + ((long)dir * 2048 + grow) * 512 + ck * 128;
    float4 wv[32];
#pragma unroll
    for (int q = 0; q < 32; ++q) wv[q] = *(const float4*)(Wrow + q * 4);

    const float* Xp = dir ? Xb : Xf;
    float* myh = hbuf + dir * 1024;
    unsigned int* mycnt = cnt + dir * 32;

    __shared__ float hs[512];
    __shared__ float ga[64];

    float c = 0.f;
    bool dead = false;

    for (int s = 0; s < 1024; ++s) {
        const int t = dir ? (1023 - s) : s;

        // stage h_{s-1} (buffer parity (s-1)&1 == (s+1)&1); zeros at s==0
        const float* hp = myh + ((s + 1) & 1) * 512;
        hs[tid]       = hp[tid];
        hs[tid + 256] = hp[tid + 256];
        __syncthreads();

        float acc = 0.f;
#pragma unroll
        for (int q = 0; q < 32; ++q) {
            float4 hv = *(const float4*)&hs[ck * 128 + q * 4];
            acc += wv[q].x * hv.x + wv[q].y * hv.y +
                   wv[q].z * hv.z + wv[q].w * hv.w;
        }
        acc += __shfl_xor(acc, 1);
        acc += __shfl_xor(acc, 2);
        if (ck == 0) ga[r] = acc + Xp[(long)t * 2048 + grow];
        __syncthreads();

        if (tid < 16) {
            float gi = ga[tid], gf = ga[16 + tid], gg = ga[32 + tid], go = ga[48 + tid];
            float i_ = 1.f / (1.f + expf(-gi));
            float f_ = 1.f / (1.f + expf(-gf));
            float g_ = tanhf(gg);
            float o_ = 1.f / (1.f + expf(-go));
            c = f_ * c + i_ * g_;
            float h = o_ * tanhf(c);
            int jj = w * 16 + tid;
            myh[(s & 1) * 512 + jj] = h;
            out[(long)t * 1024 + dir * 512 + jj] = h;
        }
        __threadfence();   // release our h writes to agent scope
        __syncthreads();
        if (tid == 0) {
            __hip_atomic_fetch_add(mycnt, 1u, __ATOMIC_RELEASE, __HIP_MEMORY_SCOPE_AGENT);
            const unsigned target = (unsigned)NW * (unsigned)(s + 1);
            if (!dead) {
                unsigned it = 0;
                while (__hip_atomic_load(mycnt, __ATOMIC_ACQUIRE, __HIP_MEMORY_SCOPE_AGENT) < target) {
                    __builtin_amdgcn_s_sleep(1);
                    if (++it > (1u << 22)) { dead = true; break; }  // anti-hang
                }
            }
        }
        __syncthreads();
        __threadfence();   // acquire: invalidate caches before reading fresh h
    }
}

// ---------------------------------------------------------------------------
__global__ __launch_bounds__(128) void gather_emb(
    const int* __restrict__ en, const float* __restrict__ emb, float* __restrict__ x0)
{
    const int t = blockIdx.x;
    ((float4*)(x0 + (long)t * 512))[threadIdx.x] =
        ((const float4*)(emb + (long)en[t] * 512))[threadIdx.x];
}

__global__ __launch_bounds__(256) void add_h(
    const float* __restrict__ o2, float* __restrict__ h)
{
    const long i = (long)blockIdx.x * 256 + threadIdx.x;   // 1024*512
    const long t = i >> 9, j = i & 511;
    h[i] = o2[t * 1024 + j] + o2[t * 1024 + 512 + j];
}

__global__ __launch_bounds__(256) void zkl_kernel(
    const float* __restrict__ mu, const float* __restrict__ sp,
    const float* __restrict__ eps, float* __restrict__ z, float* __restrict__ klsum)
{
    __shared__ float w4[4];
    const int i = blockIdx.x * 256 + threadIdx.x;
    float m = mu[i], x = sp[i];
    float sg = (x > 20.f) ? x : log1pf(expf(x));   // softplus
    z[i] = m + eps[i] * sg;
    float kl = 0.5f * (sg * sg + m * m - 1.f) - logf(sg);
#pragma unroll
    for (int o = 1; o < 64; o <<= 1) kl += __shfl_xor(kl, o);
    if ((threadIdx.x & 63) == 0) w4[threadIdx.x >> 6] = kl;
    __syncthreads();
    if (threadIdx.x == 0) atomicAdd(klsum, w4[0] + w4[1] + w4[2] + w4[3]);
}

__global__ __launch_bounds__(64) void pos_kernel(
    const float* __restrict__ z, const float* __restrict__ E_en,
    const int* __restrict__ en, float* __restrict__ pos)
{
    const int t = blockIdx.x, lane = threadIdx.x;
    const float4* zr = (const float4*)(z + (long)t * 512);
    const float4* er = (const float4*)(E_en + (long)en[t] * 512);
    float s = 0.f;
#pragma unroll
    for (int q = 0; q < 2; ++q) {
        float4 a = zr[lane + q * 64], b = er[lane + q * 64];
        s += a.x * b.x + a.y * b.y + a.z * b.z + a.w * b.w;
    }
#pragma unroll
    for (int o = 1; o < 64; o <<= 1) s += __shfl_xor(s, o);
    if (lane == 0) pos[t] = expf(s);
}

__global__ __launch_bounds__(256) void finalize_kernel(
    const float* __restrict__ pos, const float* __restrict__ neg,
    const float* __restrict__ scal, float* __restrict__ out)
{
    __shared__ float w4[4];
    const int tid = threadIdx.x;
    float s = 0.f;
#pragma unroll
    for (int q = 0; q < 4; ++q) {
        int t = tid + q * 256;
        s += pos[t] / (pos[t] + neg[t]);
    }
#pragma unroll
    for (int o = 1; o < 64; o <<= 1) s += __shfl_xor(s, o);
    if ((tid & 63) == 0) w4[tid >> 6] = s;
    __syncthreads();
    if (tid == 0) {
        float sum_x = w4[0] + w4[1] + w4[2] + w4[3];
        // -(sum_x + sum_y - kl) ; sum_y = psum/1024
        out[0] = scal[0] - sum_x - scal[1] * (1.f / 1024.f);
    }
}

// ---------------------------------------------------------------------------
extern "C" void kernel_launch(void* const* d_in, const int* in_sizes, int n_in,
                              void* d_out, int out_size, void* d_ws, size_t ws_size,
                              hipStream_t stream)
{
    const int*   en     = (const int*)d_in[0];
    const int*   fr     = (const int*)d_in[1];
    const int*   en_neg = (const int*)d_in[2];
    const int*   fr_neg = (const int*)d_in[3];
    const float* emb    = (const float*)d_in[4];
    const float* Wih0   = (const float*)d_in[5];
    const float* Whh0   = (const float*)d_in[6];
    const float* b0     = (const float*)d_in[7];
    const float* Wih1   = (const float*)d_in[8];
    const float* Whh1   = (const float*)d_in[9];
    const float* b1     = (const float*)d_in[10];
    const float* Wih2   = (const float*)d_in[11];
    const float* Whh2   = (const float*)d_in[12];
    const float* b2     = (const float*)d_in[13];
    const float* Wmu1   = (const float*)d_in[14];
    const float* bmu1   = (const float*)d_in[15];
    const float* Wmu2   = (const float*)d_in[16];
    const float* bmu2   = (const float*)d_in[17];
    const float* Ws1    = (const float*)d_in[18];
    const float* bs1    = (const float*)d_in[19];
    const float* Ws2    = (const float*)d_in[20];
    const float* bs2    = (const float*)d_in[21];
    const float* E_en   = (const float*)d_in[22];
    const float* E_fr   = (const float*)d_in[23];
    const float* eps    = (const float*)d_in[24];
    float* out = (float*)d_out;

    float* w = (float*)d_ws;
    float* x0   = w;  w += 1024 * 512;
    float* bufA = w;  w += 1024 * 1024;
    float* bufB = w;  w += 1024 * 1024;
    float* Xf   = w;  w += 1024 * 2048;
    float* Xb   = w;  w += 1024 * 2048;
    float* h    = w;  w += 1024 * 512;
    float* tmp  = w;  w += 1024 * 512;
    float* mu   = w;  w += 1024 * 512;
    float* sp   = w;  w += 1024 * 512;
    float* z    = w;  w += 1024 * 512;
    float* pos  = w;  w += 1024;
    float* neg  = w;  w += 1024;
    float* negf = w;  w += 1024;                 // neg..negf contiguous
    float* hbuf = w;  w += 2048;                 // hbuf + cnt contiguous
    unsigned int* cnt = (unsigned int*)w; w += 64;
    float* scal = w;  w += 2;                    // [klsum, psum]

    // zero accumulators (ws is poisoned 0xAA before every launch)
    hipMemsetAsync(neg, 0, 2048 * sizeof(float), stream);
    hipMemsetAsync(scal, 0, 2 * sizeof(float), stream);

    gather_emb<<<1024, 128, 0, stream>>>(en, emb, x0);

    // ---- layer 0 (in = x0, K=512) -> bufA
    gemm_nt<false, false, 0><<<dim3(16, 32), 256, 0, stream>>>(
        x0, Wih0,               b0,        nullptr, Xf, nullptr, nullptr, 1024, 2048, 512);
    gemm_nt<false, false, 0><<<dim3(16, 32), 256, 0, stream>>>(
        x0, Wih0 + 2048 * 512,  b0 + 2048, nullptr, Xb, nullptr, nullptr, 1024, 2048, 512);
    hipMemsetAsync(hbuf, 0, 2048 * sizeof(float) + 64 * sizeof(unsigned int), stream);
    lstm_scan<<<64, 256, 0, stream>>>(Xf, Xb, Whh0, bufA, hbuf, cnt);

    // ---- layer 1 (in = bufA, K=1024) -> bufB
    gemm_nt<false, false, 0><<<dim3(16, 32), 256, 0, stream>>>(
        bufA, Wih1,               b1,        nullptr, Xf, nullptr, nullptr, 1024, 2048, 1024);
    gemm_nt<false, false, 0><<<dim3(16, 32), 256, 0, stream>>>(
        bufA, Wih1 + 2048 * 1024, b1 + 2048, nullptr, Xb, nullptr, nullptr, 1024, 2048, 1024);
    hipMemsetAsync(hbuf, 0, 2048 * sizeof(float) + 64 * sizeof(unsigned int), stream);
    lstm_scan<<<64, 256, 0, stream>>>(Xf, Xb, Whh1, bufB, hbuf, cnt);

    // ---- layer 2 (in = bufB, K=1024) -> bufA
    gemm_nt<false, false, 0><<<dim3(16, 32), 256, 0, stream>>>(
        bufB, Wih2,               b2,        nullptr, Xf, nullptr, nullptr, 1024, 2048, 1024);
    gemm_nt<false, false, 0><<<dim3(16, 32), 256, 0, stream>>>(
        bufB, Wih2 + 2048 * 1024, b2 + 2048, nullptr, Xb, nullptr, nullptr, 1024, 2048, 1024);
    hipMemsetAsync(hbuf, 0, 2048 * sizeof(float) + 64 * sizeof(unsigned int), stream);
    lstm_scan<<<64, 256, 0, stream>>>(Xf, Xb, Whh2, bufA, hbuf, cnt);

    // h = hf + hb
    add_h<<<2048, 256, 0, stream>>>(bufA, h);

    // inference nets
    gemm_nt<false, true, 0><<<dim3(16, 8), 256, 0, stream>>>(
        h,   Wmu1, bmu1, nullptr, tmp, nullptr, nullptr, 1024, 512, 512);
    gemm_nt<false, false, 0><<<dim3(16, 8), 256, 0, stream>>>(
        tmp, Wmu2, bmu2, nullptr, mu,  nullptr, nullptr, 1024, 512, 512);
    gemm_nt<false, true, 0><<<dim3(16, 8), 256, 0, stream>>>(
        h,   Ws1,  bs1,  nullptr, tmp, nullptr, nullptr, 1024, 512, 512);
    gemm_nt<false, false, 0><<<dim3(16, 8), 256, 0, stream>>>(
        tmp, Ws2,  bs2,  nullptr, sp,  nullptr, nullptr, 1024, 512, 512);

    // z, KL
    zkl_kernel<<<2048, 256, 0, stream>>>(mu, sp, eps, z, scal);

    // scores
    pos_kernel<<<1024, 64, 0, stream>>>(z, E_en, en, pos);
    gemm_nt<true, false, 1><<<dim3(16, 128), 256, 0, stream>>>(
        z, E_en, nullptr, en_neg, neg,  nullptr, nullptr, 1024, 8192, 512);
    gemm_nt<true, false, 1><<<dim3(16, 128), 256, 0, stream>>>(
        z, E_fr, nullptr, fr_neg, negf, nullptr, nullptr, 1024, 8192, 512);
    gemm_nt<true, false, 2><<<dim3(16, 16), 256, 0, stream>>>(
        z, E_fr, nullptr, fr,     nullptr, negf, scal + 1, 1024, 1024, 512);

    finalize_kernel<<<1, 256, 0, stream>>>(pos, neg, scal, out);
}

// Round 2
// 11380.510 us; speedup vs baseline: 3.0960x; 3.0960x over previous
//
#include <hip/hip_runtime.h>
#include <hip/hip_bf16.h>

// EmbedAlign: emb gather -> 3-layer BiLSTM (seq scan) -> mu/sigma nets ->
// reparam z -> KL + negative-sampling scores + alignment marginal -> scalar.
// All fp32. D=512, L=1024, NNEG=8192, V=32000.

#define NW 32            // workgroups per scan direction

// ---------------------------------------------------------------------------
// Generic fp32 NT GEMM: C[M,N] = A[M,K] . B[N,K]^T (+bias) with epilogues.
// GATHER: B row n comes from B[idx[n]].  EPI: 0=store(+bias,+relu),
// 1=atomicAdd rowsum(exp(C)) into C-vector, 2=atomicAdd sum(exp/(exp+negf)).
// Tiles 64x64, BK=16, 256 threads, 4x4 per thread.
// ---------------------------------------------------------------------------
template<bool GATHER, bool RELU, int EPI>
__global__ __launch_bounds__(256) void gemm_nt(
    const float* __restrict__ A, const float* __restrict__ B,
    const float* __restrict__ bias, const int* __restrict__ idx,
    float* __restrict__ C, const float* __restrict__ negf,
    float* __restrict__ outsum, int M, int N, int K)
{
    __shared__ float As[16][68];
    __shared__ float Bs[16][68];
    __shared__ float wsum[4];

    const int tid = threadIdx.x;
    const int bm = blockIdx.x, bn = blockIdx.y;
    const int tx = tid & 15, ty = tid >> 4;
    const int lr = tid >> 2;          // 0..63: tile row being loaded
    const int lk = (tid & 3) * 4;     // 0,4,8,12: k sub-offset

    const long arow = (long)bm * 64 + lr;
    const int  brow = bn * 64 + lr;
    const long bsrc = GATHER ? (long)idx[brow] : (long)brow;
    const float* Ap = A + arow * K + lk;
    const float* Bp = B + bsrc * K + lk;

    float acc[4][4] = {};

    for (int k0 = 0; k0 < K; k0 += 16) {
        float4 av = *(const float4*)(Ap + k0);
        float4 bv = *(const float4*)(Bp + k0);
        __syncthreads();
        As[lk + 0][lr] = av.x; As[lk + 1][lr] = av.y;
        As[lk + 2][lr] = av.z; As[lk + 3][lr] = av.w;
        Bs[lk + 0][lr] = bv.x; Bs[lk + 1][lr] = bv.y;
        Bs[lk + 2][lr] = bv.z; Bs[lk + 3][lr] = bv.w;
        __syncthreads();
#pragma unroll
        for (int k = 0; k < 16; ++k) {
            float4 a = *(const float4*)&As[k][ty * 4];
            float4 b = *(const float4*)&Bs[k][tx * 4];
            float ar[4] = {a.x, a.y, a.z, a.w};
            float br[4] = {b.x, b.y, b.z, b.w};
#pragma unroll
            for (int i = 0; i < 4; ++i)
#pragma unroll
                for (int j = 0; j < 4; ++j)
                    acc[i][j] += ar[i] * br[j];
        }
    }

    const int row0 = bm * 64 + ty * 4, col0 = bn * 64 + tx * 4;

    if (EPI == 0) {
#pragma unroll
        for (int i = 0; i < 4; ++i) {
            float4 v;
            float vv[4];
#pragma unroll
            for (int j = 0; j < 4; ++j) {
                float x = acc[i][j];
                if (bias) x += bias[col0 + j];
                if (RELU) x = x > 0.f ? x : 0.f;
                vv[j] = x;
            }
            v.x = vv[0]; v.y = vv[1]; v.z = vv[2]; v.w = vv[3];
            *(float4*)&C[(long)(row0 + i) * N + col0] = v;
        }
    } else if (EPI == 1) {
        // per-row sum of exp over this tile's 64 cols -> atomicAdd C[row]
#pragma unroll
        for (int i = 0; i < 4; ++i) {
            float s = expf(acc[i][0]) + expf(acc[i][1]) +
                      expf(acc[i][2]) + expf(acc[i][3]);
            s += __shfl_xor(s, 1); s += __shfl_xor(s, 2);
            s += __shfl_xor(s, 4); s += __shfl_xor(s, 8);
            if (tx == 0) atomicAdd(&C[row0 + i], s);
        }
    } else {
        float t = 0.f;
#pragma unroll
        for (int i = 0; i < 4; ++i) {
            float nf = negf[row0 + i];
#pragma unroll
            for (int j = 0; j < 4; ++j) {
                float e = expf(acc[i][j]);
                t += e / (e + nf);
            }
        }
#pragma unroll
        for (int o = 1; o < 64; o <<= 1) t += __shfl_xor(t, o);
        if ((tid & 63) == 0) wsum[tid >> 6] = t;
        __syncthreads();
        if (tid == 0) atomicAdd(outsum, wsum[0] + wsum[1] + wsum[2] + wsum[3]);
    }
}

// ---------------------------------------------------------------------------
// BiLSTM scan over 1024 steps. Grid = 64 WGs x 256 threads:
// blocks 0..31 forward, 32..63 backward. Each WG owns 16 h-outputs (64 gate
// rows); its Whh chunk lives in registers for the whole scan.
//
// Fence-free cross-WG step barrier: ALL cross-WG traffic (h values + per-WG
// flag slots) uses relaxed agent-scope atomics (sc1 -> operate at the
// coherence point; no buffer_wbl2/buffer_inv ever needed). Writer ordering:
// h stores -> s_waitcnt vmcnt(0) (wave 0 local; sc1 store retire == visible
// at coherence point) -> flag store. Readers: poll own-direction flags
// (per-WG slot, no contention), barrier, then 8B relaxed atomic h loads.
// h double-buffered so a fast WG can't overwrite what a slow WG still reads.
// ---------------------------------------------------------------------------
__global__ __launch_bounds__(256, 1) void lstm_scan(
    const float* __restrict__ Xf, const float* __restrict__ Xb, // (1024,2048) pre-proj incl bias
    const float* __restrict__ Whh,                              // (2,2048,512)
    float* __restrict__ out,                                    // (1024,1024) [hf|hb]
    float* __restrict__ hbuf,                                   // (2 dirs,2 bufs,512), zeroed
    int* __restrict__ flags)                                    // (2 dirs,32), zeroed
{
    const int tid  = threadIdx.x;
    const int dir  = blockIdx.x >> 5;
    const int w    = blockIdx.x & 31;
    const int r    = tid >> 2;        // 0..63 gate-row within WG
    const int ck   = tid & 3;         // col chunk 0..3 (128 cols each)
    const int gate = r >> 4;
    const int jl   = r & 15;
    const int j    = w * 16 + jl;     // h index 0..511
    const int grow = gate * 512 + j;  // row in (2048 x 512) Whh

    const float* Wrow = Whh + ((long)dir * 2048 + grow) * 512 + ck * 128;
    float4 wv[32];
#pragma unroll
    for (int q = 0; q < 32; ++q) wv[q] = *(const float4*)(Wrow + q * 4);

    const float* Xp = dir ? Xb : Xf;
    float* myh = hbuf + dir * 1024;
    int* f = flags + dir * 32;

    __shared__ float hs[512];
    __shared__ float ga[64];

    float c = 0.f;
    bool dead = false;

    for (int s = 0; s < 1024; ++s) {
        const int t = dir ? (1023 - s) : s;
        float xg = Xp[(long)t * 2048 + grow];   // issue early, L2-friendly

        // ---- wait: every WG in my direction has published step s-1 ----
        if (tid < 32 && !dead) {
            unsigned it = 0;
            while (__hip_atomic_load(&f[tid], __ATOMIC_RELAXED,
                                     __HIP_MEMORY_SCOPE_AGENT) < s) {
                if (++it > (1u << 20)) { dead = true; break; }  // anti-hang
            }
        }
        __syncthreads();

        // ---- coherent fetch of h_{s-1} (parity (s+1)&1), stage to LDS ----
        const unsigned long long* hp =
            (const unsigned long long*)(myh + ((s + 1) & 1) * 512);
        unsigned long long hv8 = __hip_atomic_load(&hp[tid], __ATOMIC_RELAXED,
                                                   __HIP_MEMORY_SCOPE_AGENT);
        hs[2 * tid]     = __uint_as_float((unsigned)hv8);
        hs[2 * tid + 1] = __uint_as_float((unsigned)(hv8 >> 32));
        __syncthreads();

        float acc = 0.f;
#pragma unroll
        for (int q = 0; q < 32; ++q) {
            float4 hv = *(const float4*)&hs[ck * 128 + q * 4];
            acc += wv[q].x * hv.x + wv[q].y * hv.y +
                   wv[q].z * hv.z + wv[q].w * hv.w;
        }
        acc += __shfl_xor(acc, 1);
        acc += __shfl_xor(acc, 2);
        if (ck == 0) ga[r] = acc + xg;
        __syncthreads();

        float hval = 0.f;
        if (tid < 16) {
            float gi = ga[tid], gf = ga[16 + tid], gg = ga[32 + tid], go = ga[48 + tid];
            float i_ = 1.f / (1.f + expf(-gi));
            float f_ = 1.f / (1.f + expf(-gf));
            float g_ = tanhf(gg);
            float o_ = 1.f / (1.f + expf(-go));
            c = f_ * c + i_ * g_;
            hval = o_ * tanhf(c);
            __hip_atomic_store(&myh[(s & 1) * 512 + w * 16 + tid], hval,
                               __ATOMIC_RELAXED, __HIP_MEMORY_SCOPE_AGENT);
        }
        // wave 0 holds all writers + the flag-setter: order via vm retire
        if (tid < 64) __builtin_amdgcn_s_waitcnt(0);
        if (tid == 0)
            __hip_atomic_store(&f[w], s + 1, __ATOMIC_RELAXED,
                               __HIP_MEMORY_SCOPE_AGENT);
        if (tid < 16)
            out[(long)t * 1024 + dir * 512 + w * 16 + tid] = hval;  // off critical path
    }
}

// ---------------------------------------------------------------------------
__global__ __launch_bounds__(128) void gather_emb(
    const int* __restrict__ en, const float* __restrict__ emb, float* __restrict__ x0)
{
    const int t = blockIdx.x;
    ((float4*)(x0 + (long)t * 512))[threadIdx.x] =
        ((const float4*)(emb + (long)en[t] * 512))[threadIdx.x];
}

__global__ __launch_bounds__(256) void add_h(
    const float* __restrict__ o2, float* __restrict__ h)
{
    const long i = (long)blockIdx.x * 256 + threadIdx.x;   // 1024*512
    const long t = i >> 9, j = i & 511;
    h[i] = o2[t * 1024 + j] + o2[t * 1024 + 512 + j];
}

__global__ __launch_bounds__(256) void zkl_kernel(
    const float* __restrict__ mu, const float* __restrict__ sp,
    const float* __restrict__ eps, float* __restrict__ z, float* __restrict__ klsum)
{
    __shared__ float w4[4];
    const int i = blockIdx.x * 256 + threadIdx.x;
    float m = mu[i], x = sp[i];
    float sg = (x > 20.f) ? x : log1pf(expf(x));   // softplus
    z[i] = m + eps[i] * sg;
    float kl = 0.5f * (sg * sg + m * m - 1.f) - logf(sg);
#pragma unroll
    for (int o = 1; o < 64; o <<= 1) kl += __shfl_xor(kl, o);
    if ((threadIdx.x & 63) == 0) w4[threadIdx.x >> 6] = kl;
    __syncthreads();
    if (threadIdx.x == 0) atomicAdd(klsum, w4[0] + w4[1] + w4[2] + w4[3]);
}

__global__ __launch_bounds__(64) void pos_kernel(
    const float* __restrict__ z, const float* __restrict__ E_en,
    const int* __restrict__ en, float* __restrict__ pos)
{
    const int t = blockIdx.x, lane = threadIdx.x;
    const float4* zr = (const float4*)(z + (long)t * 512);
    const float4* er = (const float4*)(E_en + (long)en[t] * 512);
    float s = 0.f;
#pragma unroll
    for (int q = 0; q < 2; ++q) {
        float4 a = zr[lane + q * 64], b = er[lane + q * 64];
        s += a.x * b.x + a.y * b.y + a.z * b.z + a.w * b.w;
    }
#pragma unroll
    for (int o = 1; o < 64; o <<= 1) s += __shfl_xor(s, o);
    if (lane == 0) pos[t] = expf(s);
}

__global__ __launch_bounds__(256) void finalize_kernel(
    const float* __restrict__ pos, const float* __restrict__ neg,
    const float* __restrict__ scal, float* __restrict__ out)
{
    __shared__ float w4[4];
    const int tid = threadIdx.x;
    float s = 0.f;
#pragma unroll
    for (int q = 0; q < 4; ++q) {
        int t = tid + q * 256;
        s += pos[t] / (pos[t] + neg[t]);
    }
#pragma unroll
    for (int o = 1; o < 64; o <<= 1) s += __shfl_xor(s, o);
    if ((tid & 63) == 0) w4[tid >> 6] = s;
    __syncthreads();
    if (tid == 0) {
        float sum_x = w4[0] + w4[1] + w4[2] + w4[3];
        // -(sum_x + sum_y - kl) ; sum_y = psum/1024
        out[0] = scal[0] - sum_x - scal[1] * (1.f / 1024.f);
    }
}

// ---------------------------------------------------------------------------
extern "C" void kernel_launch(void* const* d_in, const int* in_sizes, int n_in,
                              void* d_out, int out_size, void* d_ws, size_t ws_size,
                              hipStream_t stream)
{
    const int*   en     = (const int*)d_in[0];
    const int*   fr     = (const int*)d_in[1];
    const int*   en_neg = (const int*)d_in[2];
    const int*   fr_neg = (const int*)d_in[3];
    const float* emb    = (const float*)d_in[4];
    const float* Wih0   = (const float*)d_in[5];
    const float* Whh0   = (const float*)d_in[6];
    const float* b0     = (const float*)d_in[7];
    const float* Wih1   = (const float*)d_in[8];
    const float* Whh1   = (const float*)d_in[9];
    const float* b1     = (const float*)d_in[10];
    const float* Wih2   = (const float*)d_in[11];
    const float* Whh2   = (const float*)d_in[12];
    const float* b2     = (const float*)d_in[13];
    const float* Wmu1   = (const float*)d_in[14];
    const float* bmu1   = (const float*)d_in[15];
    const float* Wmu2   = (const float*)d_in[16];
    const float* bmu2   = (const float*)d_in[17];
    const float* Ws1    = (const float*)d_in[18];
    const float* bs1    = (const float*)d_in[19];
    const float* Ws2    = (const float*)d_in[20];
    const float* bs2    = (const float*)d_in[21];
    const float* E_en   = (const float*)d_in[22];
    const float* E_fr   = (const float*)d_in[23];
    const float* eps    = (const float*)d_in[24];
    float* out = (float*)d_out;

    float* w = (float*)d_ws;
    float* x0   = w;  w += 1024 * 512;
    float* bufA = w;  w += 1024 * 1024;
    float* bufB = w;  w += 1024 * 1024;
    float* Xf   = w;  w += 1024 * 2048;
    float* Xb   = w;  w += 1024 * 2048;
    float* h    = w;  w += 1024 * 512;
    float* tmp  = w;  w += 1024 * 512;
    float* mu   = w;  w += 1024 * 512;
    float* sp   = w;  w += 1024 * 512;
    float* z    = w;  w += 1024 * 512;
    float* pos  = w;  w += 1024;
    float* neg  = w;  w += 1024;
    float* negf = w;  w += 1024;                 // neg..negf contiguous
    float* hbuf = w;  w += 2048;                 // hbuf + flags contiguous
    int*  flags = (int*)w; w += 64;
    float* scal = w;  w += 2;                    // [klsum, psum]

    // zero accumulators (ws is poisoned 0xAA before every launch)
    hipMemsetAsync(neg, 0, 2048 * sizeof(float), stream);
    hipMemsetAsync(scal, 0, 2 * sizeof(float), stream);

    gather_emb<<<1024, 128, 0, stream>>>(en, emb, x0);

    // ---- layer 0 (in = x0, K=512) -> bufA
    gemm_nt<false, false, 0><<<dim3(16, 32), 256, 0, stream>>>(
        x0, Wih0,               b0,        nullptr, Xf, nullptr, nullptr, 1024, 2048, 512);
    gemm_nt<false, false, 0><<<dim3(16, 32), 256, 0, stream>>>(
        x0, Wih0 + 2048 * 512,  b0 + 2048, nullptr, Xb, nullptr, nullptr, 1024, 2048, 512);
    hipMemsetAsync(hbuf, 0, 2048 * sizeof(float) + 64 * sizeof(int), stream);
    lstm_scan<<<64, 256, 0, stream>>>(Xf, Xb, Whh0, bufA, hbuf, flags);

    // ---- layer 1 (in = bufA, K=1024) -> bufB
    gemm_nt<false, false, 0><<<dim3(16, 32), 256, 0, stream>>>(
        bufA, Wih1,               b1,        nullptr, Xf, nullptr, nullptr, 1024, 2048, 1024);
    gemm_nt<false, false, 0><<<dim3(16, 32), 256, 0, stream>>>(
        bufA, Wih1 + 2048 * 1024, b1 + 2048, nullptr, Xb, nullptr, nullptr, 1024, 2048, 1024);
    hipMemsetAsync(hbuf, 0, 2048 * sizeof(float) + 64 * sizeof(int), stream);
    lstm_scan<<<64, 256, 0, stream>>>(Xf, Xb, Whh1, bufB, hbuf, flags);

    // ---- layer 2 (in = bufB, K=1024) -> bufA
    gemm_nt<false, false, 0><<<dim3(16, 32), 256, 0, stream>>>(
        bufB, Wih2,               b2,        nullptr, Xf, nullptr, nullptr, 1024, 2048, 1024);
    gemm_nt<false, false, 0><<<dim3(16, 32), 256, 0, stream>>>(
        bufB, Wih2 + 2048 * 1024, b2 + 2048, nullptr, Xb, nullptr, nullptr, 1024, 2048, 1024);
    hipMemsetAsync(hbuf, 0, 2048 * sizeof(float) + 64 * sizeof(int), stream);
    lstm_scan<<<64, 256, 0, stream>>>(Xf, Xb, Whh2, bufA, hbuf, flags);

    // h = hf + hb
    add_h<<<2048, 256, 0, stream>>>(bufA, h);

    // inference nets
    gemm_nt<false, true, 0><<<dim3(16, 8), 256, 0, stream>>>(
        h,   Wmu1, bmu1, nullptr, tmp, nullptr, nullptr, 1024, 512, 512);
    gemm_nt<false, false, 0><<<dim3(16, 8), 256, 0, stream>>>(
        tmp, Wmu2, bmu2, nullptr, mu,  nullptr, nullptr, 1024, 512, 512);
    gemm_nt<false, true, 0><<<dim3(16, 8), 256, 0, stream>>>(
        h,   Ws1,  bs1,  nullptr, tmp, nullptr, nullptr, 1024, 512, 512);
    gemm_nt<false, false, 0><<<dim3(16, 8), 256, 0, stream>>>(
        tmp, Ws2,  bs2,  nullptr, sp,  nullptr, nullptr, 1024, 512, 512);

    // z, KL
    zkl_kernel<<<2048, 256, 0, stream>>>(mu, sp, eps, z, scal);

    // scores
    pos_kernel<<<1024, 64, 0, stream>>>(z, E_en, en, pos);
    gemm_nt<true, false, 1><<<dim3(16, 128), 256, 0, stream>>>(
        z, E_en, nullptr, en_neg, neg,  nullptr, nullptr, 1024, 8192, 512);
    gemm_nt<true, false, 1><<<dim3(16, 128), 256, 0, stream>>>(
        z, E_fr, nullptr, fr_neg, negf, nullptr, nullptr, 1024, 8192, 512);
    gemm_nt<true, false, 2><<<dim3(16, 16), 256, 0, stream>>>(
        z, E_fr, nullptr, fr,     nullptr, negf, scal + 1, 1024, 1024, 512);

    finalize_kernel<<<1, 256, 0, stream>>>(pos, neg, scal, out);
}

// Round 3
// 8351.988 us; speedup vs baseline: 4.2187x; 1.3626x over previous
//
#include <hip/hip_runtime.h>
#include <hip/hip_bf16.h>

// EmbedAlign: emb gather -> 3-layer BiLSTM (seq scan) -> mu/sigma nets ->
// reparam z -> KL + negative-sampling scores + alignment marginal -> scalar.
// All fp32. D=512, L=1024, NNEG=8192, V=32000.

// ---------------------------------------------------------------------------
// Generic fp32 NT GEMM: C[M,N] = A[M,K] . B[N,K]^T (+bias) with epilogues.
// GATHER: B row n comes from B[idx[n]].  EPI: 0=store(+bias,+relu),
// 1=atomicAdd rowsum(exp(C)) into C-vector, 2=atomicAdd sum(exp/(exp+negf)).
// Tiles 64x64, BK=16, 256 threads, 4x4 per thread.
// ---------------------------------------------------------------------------
template<bool GATHER, bool RELU, int EPI>
__global__ __launch_bounds__(256) void gemm_nt(
    const float* __restrict__ A, const float* __restrict__ B,
    const float* __restrict__ bias, const int* __restrict__ idx,
    float* __restrict__ C, const float* __restrict__ negf,
    float* __restrict__ outsum, int M, int N, int K)
{
    __shared__ float As[16][68];
    __shared__ float Bs[16][68];
    __shared__ float wsum[4];

    const int tid = threadIdx.x;
    const int bm = blockIdx.x, bn = blockIdx.y;
    const int tx = tid & 15, ty = tid >> 4;
    const int lr = tid >> 2;          // 0..63: tile row being loaded
    const int lk = (tid & 3) * 4;     // 0,4,8,12: k sub-offset

    const long arow = (long)bm * 64 + lr;
    const int  brow = bn * 64 + lr;
    const long bsrc = GATHER ? (long)idx[brow] : (long)brow;
    const float* Ap = A + arow * K + lk;
    const float* Bp = B + bsrc * K + lk;

    float acc[4][4] = {};

    for (int k0 = 0; k0 < K; k0 += 16) {
        float4 av = *(const float4*)(Ap + k0);
        float4 bv = *(const float4*)(Bp + k0);
        __syncthreads();
        As[lk + 0][lr] = av.x; As[lk + 1][lr] = av.y;
        As[lk + 2][lr] = av.z; As[lk + 3][lr] = av.w;
        Bs[lk + 0][lr] = bv.x; Bs[lk + 1][lr] = bv.y;
        Bs[lk + 2][lr] = bv.z; Bs[lk + 3][lr] = bv.w;
        __syncthreads();
#pragma unroll
        for (int k = 0; k < 16; ++k) {
            float4 a = *(const float4*)&As[k][ty * 4];
            float4 b = *(const float4*)&Bs[k][tx * 4];
            float ar[4] = {a.x, a.y, a.z, a.w};
            float br[4] = {b.x, b.y, b.z, b.w};
#pragma unroll
            for (int i = 0; i < 4; ++i)
#pragma unroll
                for (int j = 0; j < 4; ++j)
                    acc[i][j] += ar[i] * br[j];
        }
    }

    const int row0 = bm * 64 + ty * 4, col0 = bn * 64 + tx * 4;

    if (EPI == 0) {
#pragma unroll
        for (int i = 0; i < 4; ++i) {
            float4 v;
            float vv[4];
#pragma unroll
            for (int j = 0; j < 4; ++j) {
                float x = acc[i][j];
                if (bias) x += bias[col0 + j];
                if (RELU) x = x > 0.f ? x : 0.f;
                vv[j] = x;
            }
            v.x = vv[0]; v.y = vv[1]; v.z = vv[2]; v.w = vv[3];
            *(float4*)&C[(long)(row0 + i) * N + col0] = v;
        }
    } else if (EPI == 1) {
        // per-row sum of exp over this tile's 64 cols -> atomicAdd C[row]
#pragma unroll
        for (int i = 0; i < 4; ++i) {
            float s = expf(acc[i][0]) + expf(acc[i][1]) +
                      expf(acc[i][2]) + expf(acc[i][3]);
            s += __shfl_xor(s, 1); s += __shfl_xor(s, 2);
            s += __shfl_xor(s, 4); s += __shfl_xor(s, 8);
            if (tx == 0) atomicAdd(&C[row0 + i], s);
        }
    } else {
        float t = 0.f;
#pragma unroll
        for (int i = 0; i < 4; ++i) {
            float nf = negf[row0 + i];
#pragma unroll
            for (int j = 0; j < 4; ++j) {
                float e = expf(acc[i][j]);
                t += e / (e + nf);
            }
        }
#pragma unroll
        for (int o = 1; o < 64; o <<= 1) t += __shfl_xor(t, o);
        if ((tid & 63) == 0) wsum[tid >> 6] = t;
        __syncthreads();
        if (tid == 0) atomicAdd(outsum, wsum[0] + wsum[1] + wsum[2] + wsum[3]);
    }
}

// ---------------------------------------------------------------------------
// BiLSTM scan, 1024 steps. Grid = 128 WGs x 256 threads: blocks 0..63
// forward, 64..127 backward. Each WG owns 8 h-outputs (32 gate rows);
// its Whh chunk is 16 float4 = 64 VGPRs per thread (8 threads/row x 64
// cols) -- small enough that the register allocator keeps it resident
// (R1's 128-float version got demoted to per-step global reloads:
// FETCH_SIZE 38 GB, VGPR_Count 84).
//
// Cross-WG step exchange: each h is published as ONE 8-byte relaxed
// agent-scope atomic (low 32 = fp32 h, high 32 = tag s+1). Readers poll
// the slots directly -- tag match means the data is already in hand; no
// separate flag, no fences, no vmcnt chaining. Buffers alternate by step
// parity; a WG can only lap a buffer after every WG published the step
// in between, which happens after they stopped reading it.
// ---------------------------------------------------------------------------
__global__ __launch_bounds__(256, 1) void lstm_scan(
    const float* __restrict__ Xf, const float* __restrict__ Xb, // (1024,2048) pre-proj incl bias
    const float* __restrict__ Whh,                              // (2,2048,512)
    float* __restrict__ out,                                    // (1024,1024) [hf|hb]
    unsigned long long* __restrict__ hbuf)                      // (2 dirs,2 bufs,512 slots), zeroed
{
    const int tid  = threadIdx.x;
    const int dir  = blockIdx.x >> 6;
    const int w    = blockIdx.x & 63;
    const int r    = tid >> 3;        // 0..31 gate-row within WG
    const int ck   = tid & 7;         // col chunk 0..7 (64 cols each)
    const int gate = r >> 3;
    const int jl   = r & 7;
    const int j    = w * 8 + jl;      // h index 0..511
    const int grow = gate * 512 + j;  // row in (2048 x 512) Whh

    const float* Wrow = Whh + ((long)dir * 2048 + grow) * 512 + ck * 64;
    float4 wv[16];
#pragma unroll
    for (int q = 0; q < 16; ++q) wv[q] = *(const float4*)(Wrow + q * 4);

    const float* Xp = dir ? Xb : Xf;
    unsigned long long* myh = hbuf + dir * 1024;

    __shared__ float hs[512];
    __shared__ float ga[32];

    float c = 0.f;
    bool dead = false;

    for (int s = 0; s < 1024; ++s) {
        const int t = dir ? (1023 - s) : s;
        float xg = Xp[(long)t * 2048 + grow];   // prefetch, off critical path

        // ---- poll h_{s-1} slots directly (tag==s) ----
        unsigned long long* rb = myh + ((s + 1) & 1) * 512;
        unsigned long long v0, v1;
        unsigned it = 0;
        for (;;) {
            v0 = __hip_atomic_load(&rb[tid],       __ATOMIC_RELAXED, __HIP_MEMORY_SCOPE_AGENT);
            v1 = __hip_atomic_load(&rb[tid + 256], __ATOMIC_RELAXED, __HIP_MEMORY_SCOPE_AGENT);
            if (dead || ((int)(v0 >> 32) == s && (int)(v1 >> 32) == s)) break;
            if (++it > (1u << 20)) { dead = true; break; }   // anti-hang
        }
        hs[tid]       = __uint_as_float((unsigned)v0);
        hs[tid + 256] = __uint_as_float((unsigned)v1);
        __syncthreads();

        // ---- 64-wide partial dot, 4 independent accumulators ----
        float a0 = 0.f, a1 = 0.f, a2 = 0.f, a3 = 0.f;
#pragma unroll
        for (int q = 0; q < 4; ++q) {
            const float4* hp4 = (const float4*)&hs[ck * 64 + q * 16];
            float4 h0 = hp4[0], h1 = hp4[1], h2 = hp4[2], h3 = hp4[3];
            float4 w0 = wv[4*q], w1 = wv[4*q+1], w2 = wv[4*q+2], w3 = wv[4*q+3];
            a0 += w0.x*h0.x + w0.y*h0.y + w0.z*h0.z + w0.w*h0.w;
            a1 += w1.x*h1.x + w1.y*h1.y + w1.z*h1.z + w1.w*h1.w;
            a2 += w2.x*h2.x + w2.y*h2.y + w2.z*h2.z + w2.w*h2.w;
            a3 += w3.x*h3.x + w3.y*h3.y + w3.z*h3.z + w3.w*h3.w;
        }
        float acc = (a0 + a1) + (a2 + a3);
        acc += __shfl_xor(acc, 1);
        acc += __shfl_xor(acc, 2);
        acc += __shfl_xor(acc, 4);
        if (ck == 0) ga[r] = acc + xg;
        __syncthreads();

        if (tid < 8) {
            float gi = ga[tid], gf = ga[8 + tid], gg = ga[16 + tid], go = ga[24 + tid];
            float i_ = 1.f / (1.f + expf(-gi));
            float f_ = 1.f / (1.f + expf(-gf));
            float g_ = tanhf(gg);
            float o_ = 1.f / (1.f + expf(-go));
            c = f_ * c + i_ * g_;
            float h = o_ * tanhf(c);
            unsigned long long pk = (unsigned long long)__float_as_uint(h)
                                  | ((unsigned long long)(unsigned)(s + 1) << 32);
            __hip_atomic_store(&myh[(s & 1) * 512 + w * 8 + tid], pk,
                               __ATOMIC_RELAXED, __HIP_MEMORY_SCOPE_AGENT);
            out[(long)t * 1024 + dir * 512 + w * 8 + tid] = h;   // off critical path
        }
    }
}

// ---------------------------------------------------------------------------
__global__ __launch_bounds__(128) void gather_emb(
    const int* __restrict__ en, const float* __restrict__ emb, float* __restrict__ x0)
{
    const int t = blockIdx.x;
    ((float4*)(x0 + (long)t * 512))[threadIdx.x] =
        ((const float4*)(emb + (long)en[t] * 512))[threadIdx.x];
}

__global__ __launch_bounds__(256) void add_h(
    const float* __restrict__ o2, float* __restrict__ h)
{
    const long i = (long)blockIdx.x * 256 + threadIdx.x;   // 1024*512
    const long t = i >> 9, j = i & 511;
    h[i] = o2[t * 1024 + j] + o2[t * 1024 + 512 + j];
}

__global__ __launch_bounds__(256) void zkl_kernel(
    const float* __restrict__ mu, const float* __restrict__ sp,
    const float* __restrict__ eps, float* __restrict__ z, float* __restrict__ klsum)
{
    __shared__ float w4[4];
    const int i = blockIdx.x * 256 + threadIdx.x;
    float m = mu[i], x = sp[i];
    float sg = (x > 20.f) ? x : log1pf(expf(x));   // softplus
    z[i] = m + eps[i] * sg;
    float kl = 0.5f * (sg * sg + m * m - 1.f) - logf(sg);
#pragma unroll
    for (int o = 1; o < 64; o <<= 1) kl += __shfl_xor(kl, o);
    if ((threadIdx.x & 63) == 0) w4[threadIdx.x >> 6] = kl;
    __syncthreads();
    if (threadIdx.x == 0) atomicAdd(klsum, w4[0] + w4[1] + w4[2] + w4[3]);
}

__global__ __launch_bounds__(64) void pos_kernel(
    const float* __restrict__ z, const float* __restrict__ E_en,
    const int* __restrict__ en, float* __restrict__ pos)
{
    const int t = blockIdx.x, lane = threadIdx.x;
    const float4* zr = (const float4*)(z + (long)t * 512);
    const float4* er = (const float4*)(E_en + (long)en[t] * 512);
    float s = 0.f;
#pragma unroll
    for (int q = 0; q < 2; ++q) {
        float4 a = zr[lane + q * 64], b = er[lane + q * 64];
        s += a.x * b.x + a.y * b.y + a.z * b.z + a.w * b.w;
    }
#pragma unroll
    for (int o = 1; o < 64; o <<= 1) s += __shfl_xor(s, o);
    if (lane == 0) pos[t] = expf(s);
}

__global__ __launch_bounds__(256) void finalize_kernel(
    const float* __restrict__ pos, const float* __restrict__ neg,
    const float* __restrict__ scal, float* __restrict__ out)
{
    __shared__ float w4[4];
    const int tid = threadIdx.x;
    float s = 0.f;
#pragma unroll
    for (int q = 0; q < 4; ++q) {
        int t = tid + q * 256;
        s += pos[t] / (pos[t] + neg[t]);
    }
#pragma unroll
    for (int o = 1; o < 64; o <<= 1) s += __shfl_xor(s, o);
    if ((tid & 63) == 0) w4[tid >> 6] = s;
    __syncthreads();
    if (tid == 0) {
        float sum_x = w4[0] + w4[1] + w4[2] + w4[3];
        // -(sum_x + sum_y - kl) ; sum_y = psum/1024
        out[0] = scal[0] - sum_x - scal[1] * (1.f / 1024.f);
    }
}

// ---------------------------------------------------------------------------
extern "C" void kernel_launch(void* const* d_in, const int* in_sizes, int n_in,
                              void* d_out, int out_size, void* d_ws, size_t ws_size,
                              hipStream_t stream)
{
    const int*   en     = (const int*)d_in[0];
    const int*   fr     = (const int*)d_in[1];
    const int*   en_neg = (const int*)d_in[2];
    const int*   fr_neg = (const int*)d_in[3];
    const float* emb    = (const float*)d_in[4];
    const float* Wih0   = (const float*)d_in[5];
    const float* Whh0   = (const float*)d_in[6];
    const float* b0     = (const float*)d_in[7];
    const float* Wih1   = (const float*)d_in[8];
    const float* Whh1   = (const float*)d_in[9];
    const float* b1     = (const float*)d_in[10];
    const float* Wih2   = (const float*)d_in[11];
    const float* Whh2   = (const float*)d_in[12];
    const float* b2     = (const float*)d_in[13];
    const float* Wmu1   = (const float*)d_in[14];
    const float* bmu1   = (const float*)d_in[15];
    const float* Wmu2   = (const float*)d_in[16];
    const float* bmu2   = (const float*)d_in[17];
    const float* Ws1    = (const float*)d_in[18];
    const float* bs1    = (const float*)d_in[19];
    const float* Ws2    = (const float*)d_in[20];
    const float* bs2    = (const float*)d_in[21];
    const float* E_en   = (const float*)d_in[22];
    const float* E_fr   = (const float*)d_in[23];
    const float* eps    = (const float*)d_in[24];
    float* out = (float*)d_out;

    float* w = (float*)d_ws;
    float* x0   = w;  w += 1024 * 512;
    float* bufA = w;  w += 1024 * 1024;
    float* bufB = w;  w += 1024 * 1024;
    float* Xf   = w;  w += 1024 * 2048;
    float* Xb   = w;  w += 1024 * 2048;
    float* h    = w;  w += 1024 * 512;
    float* tmp  = w;  w += 1024 * 512;
    float* mu   = w;  w += 1024 * 512;
    float* sp   = w;  w += 1024 * 512;
    float* z    = w;  w += 1024 * 512;
    float* pos  = w;  w += 1024;
    float* neg  = w;  w += 1024;
    float* negf = w;  w += 1024;                 // neg..negf contiguous
    unsigned long long* hbuf = (unsigned long long*)w; w += 4096;  // 2x2x512 slots x 8B
    float* scal = w;  w += 2;                    // [klsum, psum]

    // zero accumulators (ws is poisoned 0xAA before every launch)
    hipMemsetAsync(neg, 0, 2048 * sizeof(float), stream);
    hipMemsetAsync(scal, 0, 2 * sizeof(float), stream);

    gather_emb<<<1024, 128, 0, stream>>>(en, emb, x0);

    // ---- layer 0 (in = x0, K=512) -> bufA
    gemm_nt<false, false, 0><<<dim3(16, 32), 256, 0, stream>>>(
        x0, Wih0,               b0,        nullptr, Xf, nullptr, nullptr, 1024, 2048, 512);
    gemm_nt<false, false, 0><<<dim3(16, 32), 256, 0, stream>>>(
        x0, Wih0 + 2048 * 512,  b0 + 2048, nullptr, Xb, nullptr, nullptr, 1024, 2048, 512);
    hipMemsetAsync(hbuf, 0, 4096 * 8, stream);
    lstm_scan<<<128, 256, 0, stream>>>(Xf, Xb, Whh0, bufA, hbuf);

    // ---- layer 1 (in = bufA, K=1024) -> bufB
    gemm_nt<false, false, 0><<<dim3(16, 32), 256, 0, stream>>>(
        bufA, Wih1,               b1,        nullptr, Xf, nullptr, nullptr, 1024, 2048, 1024);
    gemm_nt<false, false, 0><<<dim3(16, 32), 256, 0, stream>>>(
        bufA, Wih1 + 2048 * 1024, b1 + 2048, nullptr, Xb, nullptr, nullptr, 1024, 2048, 1024);
    hipMemsetAsync(hbuf, 0, 4096 * 8, stream);
    lstm_scan<<<128, 256, 0, stream>>>(Xf, Xb, Whh1, bufB, hbuf);

    // ---- layer 2 (in = bufB, K=1024) -> bufA
    gemm_nt<false, false, 0><<<dim3(16, 32), 256, 0, stream>>>(
        bufB, Wih2,               b2,        nullptr, Xf, nullptr, nullptr, 1024, 2048, 1024);
    gemm_nt<false, false, 0><<<dim3(16, 32), 256, 0, stream>>>(
        bufB, Wih2 + 2048 * 1024, b2 + 2048, nullptr, Xb, nullptr, nullptr, 1024, 2048, 1024);
    hipMemsetAsync(hbuf, 0, 4096 * 8, stream);
    lstm_scan<<<128, 256, 0, stream>>>(Xf, Xb, Whh2, bufA, hbuf);

    // h = hf + hb
    add_h<<<2048, 256, 0, stream>>>(bufA, h);

    // inference nets
    gemm_nt<false, true, 0><<<dim3(16, 8), 256, 0, stream>>>(
        h,   Wmu1, bmu1, nullptr, tmp, nullptr, nullptr, 1024, 512, 512);
    gemm_nt<false, false, 0><<<dim3(16, 8), 256, 0, stream>>>(
        tmp, Wmu2, bmu2, nullptr, mu,  nullptr, nullptr, 1024, 512, 512);
    gemm_nt<false, true, 0><<<dim3(16, 8), 256, 0, stream>>>(
        h,   Ws1,  bs1,  nullptr, tmp, nullptr, nullptr, 1024, 512, 512);
    gemm_nt<false, false, 0><<<dim3(16, 8), 256, 0, stream>>>(
        tmp, Ws2,  bs2,  nullptr, sp,  nullptr, nullptr, 1024, 512, 512);

    // z, KL
    zkl_kernel<<<2048, 256, 0, stream>>>(mu, sp, eps, z, scal);

    // scores
    pos_kernel<<<1024, 64, 0, stream>>>(z, E_en, en, pos);
    gemm_nt<true, false, 1><<<dim3(16, 128), 256, 0, stream>>>(
        z, E_en, nullptr, en_neg, neg,  nullptr, nullptr, 1024, 8192, 512);
    gemm_nt<true, false, 1><<<dim3(16, 128), 256, 0, stream>>>(
        z, E_fr, nullptr, fr_neg, negf, nullptr, nullptr, 1024, 8192, 512);
    gemm_nt<true, false, 2><<<dim3(16, 16), 256, 0, stream>>>(
        z, E_fr, nullptr, fr,     nullptr, negf, scal + 1, 1024, 1024, 512);

    finalize_kernel<<<1, 256, 0, stream>>>(pos, neg, scal, out);
}

// Round 4
// 7147.530 us; speedup vs baseline: 4.9296x; 1.1685x over previous
//
#include <hip/hip_runtime.h>
#include <hip/hip_bf16.h>

// EmbedAlign: emb gather -> 3-layer BiLSTM (seq scan) -> mu/sigma nets ->
// reparam z -> KL + negative-sampling scores + alignment marginal -> scalar.
// All fp32. D=512, L=1024, NNEG=8192, V=32000.

// ---------------------------------------------------------------------------
// Generic fp32 NT GEMM: C[M,N] = A[M,K] . B[N,K]^T (+bias) with epilogues.
// GATHER: B row n comes from B[idx[n]].  EPI: 0=store(+bias,+relu),
// 1=atomicAdd rowsum(exp(C)) into C-vector, 2=atomicAdd sum(exp/(exp+negf)).
// Tiles 64x64, BK=16, 256 threads, 4x4 per thread.
// ---------------------------------------------------------------------------
template<bool GATHER, bool RELU, int EPI>
__global__ __launch_bounds__(256) void gemm_nt(
    const float* __restrict__ A, const float* __restrict__ B,
    const float* __restrict__ bias, const int* __restrict__ idx,
    float* __restrict__ C, const float* __restrict__ negf,
    float* __restrict__ outsum, int M, int N, int K)
{
    __shared__ float As[16][68];
    __shared__ float Bs[16][68];
    __shared__ float wsum[4];

    const int tid = threadIdx.x;
    const int bm = blockIdx.x, bn = blockIdx.y;
    const int tx = tid & 15, ty = tid >> 4;
    const int lr = tid >> 2;          // 0..63: tile row being loaded
    const int lk = (tid & 3) * 4;     // 0,4,8,12: k sub-offset

    const long arow = (long)bm * 64 + lr;
    const int  brow = bn * 64 + lr;
    const long bsrc = GATHER ? (long)idx[brow] : (long)brow;
    const float* Ap = A + arow * K + lk;
    const float* Bp = B + bsrc * K + lk;

    float acc[4][4] = {};

    for (int k0 = 0; k0 < K; k0 += 16) {
        float4 av = *(const float4*)(Ap + k0);
        float4 bv = *(const float4*)(Bp + k0);
        __syncthreads();
        As[lk + 0][lr] = av.x; As[lk + 1][lr] = av.y;
        As[lk + 2][lr] = av.z; As[lk + 3][lr] = av.w;
        Bs[lk + 0][lr] = bv.x; Bs[lk + 1][lr] = bv.y;
        Bs[lk + 2][lr] = bv.z; Bs[lk + 3][lr] = bv.w;
        __syncthreads();
#pragma unroll
        for (int k = 0; k < 16; ++k) {
            float4 a = *(const float4*)&As[k][ty * 4];
            float4 b = *(const float4*)&Bs[k][tx * 4];
            float ar[4] = {a.x, a.y, a.z, a.w};
            float br[4] = {b.x, b.y, b.z, b.w};
#pragma unroll
            for (int i = 0; i < 4; ++i)
#pragma unroll
                for (int j = 0; j < 4; ++j)
                    acc[i][j] += ar[i] * br[j];
        }
    }

    const int row0 = bm * 64 + ty * 4, col0 = bn * 64 + tx * 4;

    if (EPI == 0) {
#pragma unroll
        for (int i = 0; i < 4; ++i) {
            float4 v;
            float vv[4];
#pragma unroll
            for (int j = 0; j < 4; ++j) {
                float x = acc[i][j];
                if (bias) x += bias[col0 + j];
                if (RELU) x = x > 0.f ? x : 0.f;
                vv[j] = x;
            }
            v.x = vv[0]; v.y = vv[1]; v.z = vv[2]; v.w = vv[3];
            *(float4*)&C[(long)(row0 + i) * N + col0] = v;
        }
    } else if (EPI == 1) {
        // per-row sum of exp over this tile's 64 cols -> atomicAdd C[row]
#pragma unroll
        for (int i = 0; i < 4; ++i) {
            float s = expf(acc[i][0]) + expf(acc[i][1]) +
                      expf(acc[i][2]) + expf(acc[i][3]);
            s += __shfl_xor(s, 1); s += __shfl_xor(s, 2);
            s += __shfl_xor(s, 4); s += __shfl_xor(s, 8);
            if (tx == 0) atomicAdd(&C[row0 + i], s);
        }
    } else {
        float t = 0.f;
#pragma unroll
        for (int i = 0; i < 4; ++i) {
            float nf = negf[row0 + i];
#pragma unroll
            for (int j = 0; j < 4; ++j) {
                float e = expf(acc[i][j]);
                t += e / (e + nf);
            }
        }
#pragma unroll
        for (int o = 1; o < 64; o <<= 1) t += __shfl_xor(t, o);
        if ((tid & 63) == 0) wsum[tid >> 6] = t;
        __syncthreads();
        if (tid == 0) atomicAdd(outsum, wsum[0] + wsum[1] + wsum[2] + wsum[3]);
    }
}

// ---------------------------------------------------------------------------
// BiLSTM scan, 1024 steps. Grid = 256 WGs x 256 threads: blocks 0..127
// forward, 128..255 backward (1 WG/CU). Each WG owns 4 h-outputs (16 gate
// rows). Whh chunk (16 rows x 512) is staged ONCE into LDS in a per-thread-
// contiguous padded layout (stride 36 floats => bank = 4*tid%32, the
// measured conflict-free b128 pattern) -- the register allocator demoted
// register-resident weights two rounds running (VGPR_Count 84 then 52,
// per-step global reloads), LDS cannot be demoted. h staging buffer uses
// stride-36 chunks so the broadcast dot reads are also conflict-free
// (R2: SQ_LDS_BANK_CONFLICT 2.35e8 = ~1790 cy/WG/step on hs reads).
//
// Cross-WG step exchange: each h published as ONE 8-byte relaxed
// agent-scope atomic (low 32 = fp32 h, high 32 = tag s+1); readers poll
// slots directly. Buffers alternate by parity; tag s+1 on all slots
// implies every WG consumed h_{s-1}, so overwrite is safe.
// ---------------------------------------------------------------------------
__global__ __launch_bounds__(256, 1) void lstm_scan(
    const float* __restrict__ Xf, const float* __restrict__ Xb, // (1024,2048) pre-proj incl bias
    const float* __restrict__ Whh,                              // (2,2048,512)
    float* __restrict__ out,                                    // (1024,1024) [hf|hb]
    unsigned long long* __restrict__ hbuf)                      // (2 dirs,2 bufs,512 slots), zeroed
{
    const int tid  = threadIdx.x;
    const int dir  = blockIdx.x >> 7;
    const int w    = blockIdx.x & 127;
    const int r    = tid >> 4;        // 0..15 gate-row within WG
    const int ck   = tid & 15;        // col chunk 0..15 (32 cols each)
    const int gate = r >> 2;
    const int jl   = r & 3;
    const int j    = w * 4 + jl;      // h index 0..511
    const int grow = gate * 512 + j;  // row in (2048 x 512) Whh

    __shared__ float Wl[256 * 36];    // per-thread 32 w + 4 pad
    __shared__ float hs[16 * 36];     // 16 chunks of 32 h + 4 pad
    __shared__ float ga[16];

    // ---- stage this WG's Whh chunk into LDS (once) ----
    {
        const float4* Wrow = (const float4*)(Whh + ((long)dir * 2048 + grow) * 512 + ck * 32);
        float4* wl4 = (float4*)Wl + tid * 9;
#pragma unroll
        for (int q = 0; q < 8; ++q) wl4[q] = Wrow[q];
    }
    __syncthreads();

    const float* Xp = dir ? Xb : Xf;
    unsigned long long* myh = hbuf + dir * 1024;

    float c = 0.f;
    bool dead = false;

    const float4* wl4 = (const float4*)Wl + tid * 9;
    const float4* hs4 = (const float4*)hs + ck * 9;

    for (int s = 0; s < 1024; ++s) {
        const int t = dir ? (1023 - s) : s;
        float xg = Xp[(long)t * 2048 + grow];   // prefetch, off critical path

        // ---- poll h_{s-1} slots (tag==s) ----
        unsigned long long* rb = myh + ((s + 1) & 1) * 512;
        unsigned long long v0, v1;
        unsigned it = 0;
        for (;;) {
            v0 = __hip_atomic_load(&rb[tid],       __ATOMIC_RELAXED, __HIP_MEMORY_SCOPE_AGENT);
            v1 = __hip_atomic_load(&rb[tid + 256], __ATOMIC_RELAXED, __HIP_MEMORY_SCOPE_AGENT);
            if (dead || ((int)(v0 >> 32) == s && (int)(v1 >> 32) == s)) break;
            if (++it > (1u << 20)) { dead = true; break; }   // anti-hang
        }
        // stage into padded chunks: slot i -> hs[(i>>5)*36 + (i&31)]
        hs[((tid) >> 5) * 36 + (tid & 31)]             = __uint_as_float((unsigned)v0);
        hs[((tid + 256) >> 5) * 36 + (tid & 31)]       = __uint_as_float((unsigned)v1);
        __syncthreads();

        // ---- 32-wide partial dot (8 float4 pairs), conflict-free LDS ----
        float a0 = 0.f, a1 = 0.f;
#pragma unroll
        for (int q = 0; q < 8; q += 2) {
            float4 w0 = wl4[q],     h0 = hs4[q];
            float4 w1 = wl4[q + 1], h1 = hs4[q + 1];
            a0 += w0.x*h0.x + w0.y*h0.y + w0.z*h0.z + w0.w*h0.w;
            a1 += w1.x*h1.x + w1.y*h1.y + w1.z*h1.z + w1.w*h1.w;
        }
        float acc = a0 + a1;
        acc += __shfl_xor(acc, 1);
        acc += __shfl_xor(acc, 2);
        acc += __shfl_xor(acc, 4);
        acc += __shfl_xor(acc, 8);
        if (ck == 0) ga[r] = acc + xg;
        __syncthreads();

        if (tid < 4) {
            float gi = ga[tid], gf = ga[4 + tid], gg = ga[8 + tid], go = ga[12 + tid];
            float i_ = 1.f / (1.f + __expf(-gi));
            float f_ = 1.f / (1.f + __expf(-gf));
            float eg = __expf(2.f * gg);
            float g_ = (eg - 1.f) / (eg + 1.f);
            float o_ = 1.f / (1.f + __expf(-go));
            c = f_ * c + i_ * g_;
            float ec = __expf(2.f * c);
            float tc = (ec - 1.f) / (ec + 1.f);
            float h = o_ * tc;
            unsigned long long pk = (unsigned long long)__float_as_uint(h)
                                  | ((unsigned long long)(unsigned)(s + 1) << 32);
            __hip_atomic_store(&myh[(s & 1) * 512 + w * 4 + tid], pk,
                               __ATOMIC_RELAXED, __HIP_MEMORY_SCOPE_AGENT);
            out[(long)t * 1024 + dir * 512 + w * 4 + tid] = h;   // off critical path
        }
    }
}

// ---------------------------------------------------------------------------
__global__ __launch_bounds__(128) void gather_emb(
    const int* __restrict__ en, const float* __restrict__ emb, float* __restrict__ x0)
{
    const int t = blockIdx.x;
    ((float4*)(x0 + (long)t * 512))[threadIdx.x] =
        ((const float4*)(emb + (long)en[t] * 512))[threadIdx.x];
}

__global__ __launch_bounds__(256) void add_h(
    const float* __restrict__ o2, float* __restrict__ h)
{
    const long i = (long)blockIdx.x * 256 + threadIdx.x;   // 1024*512
    const long t = i >> 9, j = i & 511;
    h[i] = o2[t * 1024 + j] + o2[t * 1024 + 512 + j];
}

__global__ __launch_bounds__(256) void zkl_kernel(
    const float* __restrict__ mu, const float* __restrict__ sp,
    const float* __restrict__ eps, float* __restrict__ z, float* __restrict__ klsum)
{
    __shared__ float w4[4];
    const int i = blockIdx.x * 256 + threadIdx.x;
    float m = mu[i], x = sp[i];
    float sg = (x > 20.f) ? x : log1pf(expf(x));   // softplus
    z[i] = m + eps[i] * sg;
    float kl = 0.5f * (sg * sg + m * m - 1.f) - logf(sg);
#pragma unroll
    for (int o = 1; o < 64; o <<= 1) kl += __shfl_xor(kl, o);
    if ((threadIdx.x & 63) == 0) w4[threadIdx.x >> 6] = kl;
    __syncthreads();
    if (threadIdx.x == 0) atomicAdd(klsum, w4[0] + w4[1] + w4[2] + w4[3]);
}

__global__ __launch_bounds__(64) void pos_kernel(
    const float* __restrict__ z, const float* __restrict__ E_en,
    const int* __restrict__ en, float* __restrict__ pos)
{
    const int t = blockIdx.x, lane = threadIdx.x;
    const float4* zr = (const float4*)(z + (long)t * 512);
    const float4* er = (const float4*)(E_en + (long)en[t] * 512);
    float s = 0.f;
#pragma unroll
    for (int q = 0; q < 2; ++q) {
        float4 a = zr[lane + q * 64], b = er[lane + q * 64];
        s += a.x * b.x + a.y * b.y + a.z * b.z + a.w * b.w;
    }
#pragma unroll
    for (int o = 1; o < 64; o <<= 1) s += __shfl_xor(s, o);
    if (lane == 0) pos[t] = expf(s);
}

__global__ __launch_bounds__(256) void finalize_kernel(
    const float* __restrict__ pos, const float* __restrict__ neg,
    const float* __restrict__ scal, float* __restrict__ out)
{
    __shared__ float w4[4];
    const int tid = threadIdx.x;
    float s = 0.f;
#pragma unroll
    for (int q = 0; q < 4; ++q) {
        int t = tid + q * 256;
        s += pos[t] / (pos[t] + neg[t]);
    }
#pragma unroll
    for (int o = 1; o < 64; o <<= 1) s += __shfl_xor(s, o);
    if ((tid & 63) == 0) w4[tid >> 6] = s;
    __syncthreads();
    if (tid == 0) {
        float sum_x = w4[0] + w4[1] + w4[2] + w4[3];
        // -(sum_x + sum_y - kl) ; sum_y = psum/1024
        out[0] = scal[0] - sum_x - scal[1] * (1.f / 1024.f);
    }
}

// ---------------------------------------------------------------------------
extern "C" void kernel_launch(void* const* d_in, const int* in_sizes, int n_in,
                              void* d_out, int out_size, void* d_ws, size_t ws_size,
                              hipStream_t stream)
{
    const int*   en     = (const int*)d_in[0];
    const int*   fr     = (const int*)d_in[1];
    const int*   en_neg = (const int*)d_in[2];
    const int*   fr_neg = (const int*)d_in[3];
    const float* emb    = (const float*)d_in[4];
    const float* Wih0   = (const float*)d_in[5];
    const float* Whh0   = (const float*)d_in[6];
    const float* b0     = (const float*)d_in[7];
    const float* Wih1   = (const float*)d_in[8];
    const float* Whh1   = (const float*)d_in[9];
    const float* b1     = (const float*)d_in[10];
    const float* Wih2   = (const float*)d_in[11];
    const float* Whh2   = (const float*)d_in[12];
    const float* b2     = (const float*)d_in[13];
    const float* Wmu1   = (const float*)d_in[14];
    const float* bmu1   = (const float*)d_in[15];
    const float* Wmu2   = (const float*)d_in[16];
    const float* bmu2   = (const float*)d_in[17];
    const float* Ws1    = (const float*)d_in[18];
    const float* bs1    = (const float*)d_in[19];
    const float* Ws2    = (const float*)d_in[20];
    const float* bs2    = (const float*)d_in[21];
    const float* E_en   = (const float*)d_in[22];
    const float* E_fr   = (const float*)d_in[23];
    const float* eps    = (const float*)d_in[24];
    float* out = (float*)d_out;

    float* w = (float*)d_ws;
    float* x0   = w;  w += 1024 * 512;
    float* bufA = w;  w += 1024 * 1024;
    float* bufB = w;  w += 1024 * 1024;
    float* Xf   = w;  w += 1024 * 2048;
    float* Xb   = w;  w += 1024 * 2048;
    float* h    = w;  w += 1024 * 512;
    float* tmp  = w;  w += 1024 * 512;
    float* mu   = w;  w += 1024 * 512;
    float* sp   = w;  w += 1024 * 512;
    float* z    = w;  w += 1024 * 512;
    float* pos  = w;  w += 1024;
    float* neg  = w;  w += 1024;
    float* negf = w;  w += 1024;                 // neg..negf contiguous
    unsigned long long* hbuf = (unsigned long long*)w; w += 4096;  // 2x2x512 slots x 8B
    float* scal = w;  w += 2;                    // [klsum, psum]

    // zero accumulators (ws is poisoned 0xAA before every launch)
    hipMemsetAsync(neg, 0, 2048 * sizeof(float), stream);
    hipMemsetAsync(scal, 0, 2 * sizeof(float), stream);

    gather_emb<<<1024, 128, 0, stream>>>(en, emb, x0);

    // ---- layer 0 (in = x0, K=512) -> bufA
    gemm_nt<false, false, 0><<<dim3(16, 32), 256, 0, stream>>>(
        x0, Wih0,               b0,        nullptr, Xf, nullptr, nullptr, 1024, 2048, 512);
    gemm_nt<false, false, 0><<<dim3(16, 32), 256, 0, stream>>>(
        x0, Wih0 + 2048 * 512,  b0 + 2048, nullptr, Xb, nullptr, nullptr, 1024, 2048, 512);
    hipMemsetAsync(hbuf, 0, 4096 * 8, stream);
    lstm_scan<<<256, 256, 0, stream>>>(Xf, Xb, Whh0, bufA, hbuf);

    // ---- layer 1 (in = bufA, K=1024) -> bufB
    gemm_nt<false, false, 0><<<dim3(16, 32), 256, 0, stream>>>(
        bufA, Wih1,               b1,        nullptr, Xf, nullptr, nullptr, 1024, 2048, 1024);
    gemm_nt<false, false, 0><<<dim3(16, 32), 256, 0, stream>>>(
        bufA, Wih1 + 2048 * 1024, b1 + 2048, nullptr, Xb, nullptr, nullptr, 1024, 2048, 1024);
    hipMemsetAsync(hbuf, 0, 4096 * 8, stream);
    lstm_scan<<<256, 256, 0, stream>>>(Xf, Xb, Whh1, bufB, hbuf);

    // ---- layer 2 (in = bufB, K=1024) -> bufA
    gemm_nt<false, false, 0><<<dim3(16, 32), 256, 0, stream>>>(
        bufB, Wih2,               b2,        nullptr, Xf, nullptr, nullptr, 1024, 2048, 1024);
    gemm_nt<false, false, 0><<<dim3(16, 32), 256, 0, stream>>>(
        bufB, Wih2 + 2048 * 1024, b2 + 2048, nullptr, Xb, nullptr, nullptr, 1024, 2048, 1024);
    hipMemsetAsync(hbuf, 0, 4096 * 8, stream);
    lstm_scan<<<256, 256, 0, stream>>>(Xf, Xb, Whh2, bufA, hbuf);

    // h = hf + hb
    add_h<<<2048, 256, 0, stream>>>(bufA, h);

    // inference nets
    gemm_nt<false, true, 0><<<dim3(16, 8), 256, 0, stream>>>(
        h,   Wmu1, bmu1, nullptr, tmp, nullptr, nullptr, 1024, 512, 512);
    gemm_nt<false, false, 0><<<dim3(16, 8), 256, 0, stream>>>(
        tmp, Wmu2, bmu2, nullptr, mu,  nullptr, nullptr, 1024, 512, 512);
    gemm_nt<false, true, 0><<<dim3(16, 8), 256, 0, stream>>>(
        h,   Ws1,  bs1,  nullptr, tmp, nullptr, nullptr, 1024, 512, 512);
    gemm_nt<false, false, 0><<<dim3(16, 8), 256, 0, stream>>>(
        tmp, Ws2,  bs2,  nullptr, sp,  nullptr, nullptr, 1024, 512, 512);

    // z, KL
    zkl_kernel<<<2048, 256, 0, stream>>>(mu, sp, eps, z, scal);

    // scores
    pos_kernel<<<1024, 64, 0, stream>>>(z, E_en, en, pos);
    gemm_nt<true, false, 1><<<dim3(16, 128), 256, 0, stream>>>(
        z, E_en, nullptr, en_neg, neg,  nullptr, nullptr, 1024, 8192, 512);
    gemm_nt<true, false, 1><<<dim3(16, 128), 256, 0, stream>>>(
        z, E_fr, nullptr, fr_neg, negf, nullptr, nullptr, 1024, 8192, 512);
    gemm_nt<true, false, 2><<<dim3(16, 16), 256, 0, stream>>>(
        z, E_fr, nullptr, fr,     nullptr, negf, scal + 1, 1024, 1024, 512);

    finalize_kernel<<<1, 256, 0, stream>>>(pos, neg, scal, out);
}